// Round 1
// baseline (3933.165 us; speedup 1.0000x reference)
//
#include <hip/hip_runtime.h>
#include <math.h>

// Problem constants
#define B_TOT   2048
#define N_IN    1024
#define N_H     1024
#define N_OUT   512
#define N_UPD   1536
#define T_TOT   3072   // MAX_STEPS * N_UPD

// ---------------- prep kernels ----------------

// W1T[c*1024 + r] = W1[r*1024 + c]   (f32 transpose, coalesced writes)
__global__ void prep_w1t(const float* __restrict__ W1, float* __restrict__ W1T) {
    int idx = blockIdx.x * 256 + threadIdx.x;   // < 1024*1024
    int r = idx & 1023;        // fast dim
    int c = idx >> 10;
    W1T[(size_t)c * 1024 + r] = W1[(size_t)r * 1024 + c];
}

// W2Td[c*512 + r] = (double)W2[r*1024 + c]; W2Tf same in f32 (coalesced writes)
__global__ void prep_w2a(const float* __restrict__ W2, double* __restrict__ W2Td,
                         float* __restrict__ W2Tf) {
    int idx = blockIdx.x * 256 + threadIdx.x;   // < 512*1024
    int r = idx & 511;         // W2 row (fast)
    int c = idx >> 9;          // W2 col
    float v = W2[(size_t)r * 1024 + c];
    W2Td[(size_t)c * 512 + r] = (double)v;
    W2Tf[(size_t)c * 512 + r] = v;
}

// W2d[idx] = (double)W2[idx]  (row-major widen, coalesced)
__global__ void prep_w2b(const float* __restrict__ W2, double* __restrict__ W2d) {
    int idx = blockIdx.x * 256 + threadIdx.x;   // < 512*1024
    W2d[idx] = (double)W2[idx];
}

// ---------------- init fields (fp64) ----------------
// h1[b][m] = b1[m] + sum_i x[b][i]*W1[m][i] + sum_j s2[b][j]*W2[j][m]
// h2[b][m'] = b2[m'] + sum_j s1[b][j]*W2[m'][j]
// One wg per 8 batch rows; binary gating => adds only, uniform branches.
__global__ __launch_bounds__(256) void init_fields(
    const float* __restrict__ x, const float* __restrict__ s1i, const float* __restrict__ s2i,
    const float* __restrict__ W1T, const float* __restrict__ W2, const float* __restrict__ W2Tf,
    const float* __restrict__ b1, const float* __restrict__ b2,
    double* __restrict__ h1g, double* __restrict__ h2g)
{
    const int tid = threadIdx.x;
    const int b0 = blockIdx.x * 8;

    __shared__ unsigned char xm[1024];
    __shared__ unsigned char s2msk[512];
    __shared__ unsigned char s1msk[1024];

    for (int i = tid; i < 1024; i += 256) {
        unsigned m = 0;
        #pragma unroll
        for (int b = 0; b < 8; ++b) m |= (x[(size_t)(b0 + b) * 1024 + i] != 0.0f) << b;
        xm[i] = (unsigned char)m;
    }
    for (int j = tid; j < 512; j += 256) {
        unsigned m = 0;
        #pragma unroll
        for (int b = 0; b < 8; ++b) m |= (s2i[(size_t)(b0 + b) * 512 + j] != 0.0f) << b;
        s2msk[j] = (unsigned char)m;
    }
    for (int j = tid; j < 1024; j += 256) {
        unsigned m = 0;
        #pragma unroll
        for (int b = 0; b < 8; ++b) m |= (s1i[(size_t)(b0 + b) * 1024 + j] != 0.0f) << b;
        s1msk[j] = (unsigned char)m;
    }
    __syncthreads();

    // h1r[k*8 + b] : m = k*256 + tid, k<4, b<8
    double h1r[32];
    #pragma unroll
    for (int k = 0; k < 4; ++k) {
        double bv = (double)b1[k * 256 + tid];
        #pragma unroll
        for (int b = 0; b < 8; ++b) h1r[k * 8 + b] = bv;
    }
    // h2r[k*8 + b] : m' = k*256 + tid, k<2
    double h2r[16];
    #pragma unroll
    for (int k = 0; k < 2; ++k) {
        double bv = (double)b2[k * 256 + tid];
        #pragma unroll
        for (int b = 0; b < 8; ++b) h2r[k * 8 + b] = bv;
    }

    // x @ W1^T part (rows of W1T), software-pipelined depth 1
    {
        const float* p = W1T + tid;
        float w0n = p[0], w1n = p[256], w2n = p[512], w3n = p[768];
        for (int i = 0; i < 1024; ++i) {
            float w0 = w0n, w1 = w1n, w2 = w2n, w3 = w3n;
            if (i + 1 < 1024) {
                const float* q = W1T + (size_t)(i + 1) * 1024 + tid;
                w0n = q[0]; w1n = q[256]; w2n = q[512]; w3n = q[768];
            }
            unsigned m8 = (unsigned)__builtin_amdgcn_readfirstlane((int)xm[i]);
            if (m8) {
                double d0 = (double)w0, d1 = (double)w1, d2 = (double)w2, d3 = (double)w3;
                #pragma unroll
                for (int b = 0; b < 8; ++b) if ((m8 >> b) & 1u) {
                    h1r[0 * 8 + b] += d0; h1r[1 * 8 + b] += d1;
                    h1r[2 * 8 + b] += d2; h1r[3 * 8 + b] += d3;
                }
            }
        }
    }
    // s2 @ W2 part (rows of W2)
    {
        const float* p = W2 + tid;
        float w0n = p[0], w1n = p[256], w2n = p[512], w3n = p[768];
        for (int j = 0; j < 512; ++j) {
            float w0 = w0n, w1 = w1n, w2 = w2n, w3 = w3n;
            if (j + 1 < 512) {
                const float* q = W2 + (size_t)(j + 1) * 1024 + tid;
                w0n = q[0]; w1n = q[256]; w2n = q[512]; w3n = q[768];
            }
            unsigned m8 = (unsigned)__builtin_amdgcn_readfirstlane((int)s2msk[j]);
            if (m8) {
                double d0 = (double)w0, d1 = (double)w1, d2 = (double)w2, d3 = (double)w3;
                #pragma unroll
                for (int b = 0; b < 8; ++b) if ((m8 >> b) & 1u) {
                    h1r[0 * 8 + b] += d0; h1r[1 * 8 + b] += d1;
                    h1r[2 * 8 + b] += d2; h1r[3 * 8 + b] += d3;
                }
            }
        }
    }
    // s1 @ W2^T part (rows of W2Tf)
    {
        const float* p = W2Tf + tid;
        float w0n = p[0], w1n = p[256];
        for (int j = 0; j < 1024; ++j) {
            float w0 = w0n, w1 = w1n;
            if (j + 1 < 1024) {
                const float* q = W2Tf + (size_t)(j + 1) * 512 + tid;
                w0n = q[0]; w1n = q[256];
            }
            unsigned m8 = (unsigned)__builtin_amdgcn_readfirstlane((int)s1msk[j]);
            if (m8) {
                double d0 = (double)w0, d1 = (double)w1;
                #pragma unroll
                for (int b = 0; b < 8; ++b) if ((m8 >> b) & 1u) {
                    h2r[0 * 8 + b] += d0; h2r[1 * 8 + b] += d1;
                }
            }
        }
    }

    #pragma unroll
    for (int k = 0; k < 4; ++k)
        #pragma unroll
        for (int b = 0; b < 8; ++b)
            h1g[(size_t)(b0 + b) * 1024 + k * 256 + tid] = h1r[k * 8 + b];
    #pragma unroll
    for (int k = 0; k < 2; ++k)
        #pragma unroll
        for (int b = 0; b < 8; ++b)
            h2g[(size_t)(b0 + b) * 512 + k * 256 + tid] = h2r[k * 8 + b];
}

// ---------------- Gibbs chain kernel ----------------
// One wg per 4 batch rows (512 wgs, 2/CU). Fields in registers:
//   h1r[k*4+b] : m  = k*256 + tid, k<4, b<4   (owner of unit n: tid==n&255, blk=n>>8)
//   h2r[k*4+b] : m' = k*256 + tid, k<2
// Per update: owner compares gap vs precomputed T*logit(u) (LDS ring), publishes
// flip/sign mask via LDS; one barrier; all threads apply the rank-1 field update
// from depth-2 prefetched W row registers.
__global__ __launch_bounds__(256, 2) void gibbs(
    const float* __restrict__ x, const float* __restrict__ u, const int* __restrict__ ids,
    const double* __restrict__ W2Td, const double* __restrict__ W2d,
    const double* __restrict__ h1g, const double* __restrict__ h2g,
    const float* __restrict__ s1i, const float* __restrict__ s2i,
    float* __restrict__ out)
{
    const int tid = threadIdx.x;
    const int b0 = blockIdx.x * 4;

    __shared__ int ids_s[T_TOT];
    __shared__ double thr_s[256 * 4];   // ring: 256 updates x 4 batch
    __shared__ unsigned dslot[2];

    for (int i = tid; i < T_TOT; i += 256) ids_s[i] = ids[i];

    // load fields
    double h1r[16], h2r[8];
    #pragma unroll
    for (int k = 0; k < 4; ++k)
        #pragma unroll
        for (int b = 0; b < 4; ++b)
            h1r[k * 4 + b] = h1g[(size_t)(b0 + b) * 1024 + k * 256 + tid];
    #pragma unroll
    for (int k = 0; k < 2; ++k)
        #pragma unroll
        for (int b = 0; b < 4; ++b)
            h2r[k * 4 + b] = h2g[(size_t)(b0 + b) * 512 + k * 256 + tid];

    // state masks (bit k*4+b)
    unsigned s1m = 0, s2m = 0;
    #pragma unroll
    for (int k = 0; k < 4; ++k)
        #pragma unroll
        for (int b = 0; b < 4; ++b)
            if (s1i[(size_t)(b0 + b) * 1024 + k * 256 + tid] != 0.0f) s1m |= 1u << (k * 4 + b);
    #pragma unroll
    for (int k = 0; k < 2; ++k)
        #pragma unroll
        for (int b = 0; b < 4; ++b)
            if (s2i[(size_t)(b0 + b) * 512 + k * 256 + tid] != 0.0f) s2m |= 1u << (k * 4 + b);

    // threshold ring refill: window [t0, t0+127], 2 threads per t covering 4 b
    auto refill = [&](int t0) {
        int tt = t0 + (tid >> 1);
        if (tt < T_TOT) {
            int sweep = (tt >= N_UPD) ? 1 : 0;
            double T = (double)(float)(2.0 / exp((double)sweep / 5.0));
            const float* up = u + (size_t)tt * 2048 + b0 + (tid & 1) * 2;
            double u0 = (double)up[0], u1 = (double)up[1];
            double l0 = T * (log(u0) - log1p(-u0));
            double l1 = T * (log(u1) - log1p(-u1));
            int slot = (tt & 255) * 4 + (tid & 1) * 2;
            thr_s[slot] = l0;
            thr_s[slot + 1] = l1;
        }
    };

    auto loadrow = [&](int n, double* w) {
        if (n < N_H) {
            const double* p = W2Td + (size_t)n * 512 + tid;
            w[0] = p[0]; w[1] = p[256];
        } else {
            const double* p = W2d + (size_t)(n - N_H) * 1024 + tid;
            w[0] = p[0]; w[1] = p[256]; w[2] = p[512]; w[3] = p[768];
        }
    };

    auto step = [&](int t, double* w, int n) {
        // owner phase
        if (n < N_H) {
            if (tid == (n & 255)) {
                int blk = n >> 8;
                int tb = (t & 255) * 4;
                double th0 = thr_s[tb], th1 = thr_s[tb + 1], th2 = thr_s[tb + 2], th3 = thr_s[tb + 3];
                unsigned act = 0;
                #pragma unroll
                for (int kk = 0; kk < 4; ++kk) if (blk == kk) {
                    act = (h1r[4 * kk + 0] > th0 ? 1u : 0u) | (h1r[4 * kk + 1] > th1 ? 2u : 0u)
                        | (h1r[4 * kk + 2] > th2 ? 4u : 0u) | (h1r[4 * kk + 3] > th3 ? 8u : 0u);
                }
                unsigned old = (s1m >> (4 * blk)) & 0xFu;
                unsigned chg = act ^ old;
                s1m ^= chg << (4 * blk);
                dslot[t & 1] = chg | (act << 8);
            }
        } else {
            int nn = n - N_H;
            if (tid == (nn & 255)) {
                int blk = nn >> 8;
                int tb = (t & 255) * 4;
                double th0 = thr_s[tb], th1 = thr_s[tb + 1], th2 = thr_s[tb + 2], th3 = thr_s[tb + 3];
                unsigned act = 0;
                #pragma unroll
                for (int kk = 0; kk < 2; ++kk) if (blk == kk) {
                    act = (h2r[4 * kk + 0] > th0 ? 1u : 0u) | (h2r[4 * kk + 1] > th1 ? 2u : 0u)
                        | (h2r[4 * kk + 2] > th2 ? 4u : 0u) | (h2r[4 * kk + 3] > th3 ? 8u : 0u);
                }
                unsigned old = (s2m >> (4 * blk)) & 0xFu;
                unsigned chg = act ^ old;
                s2m ^= chg << (4 * blk);
                dslot[t & 1] = chg | (act << 8);
            }
        }
        __syncthreads();
        unsigned ms = (unsigned)__builtin_amdgcn_readfirstlane((int)dslot[t & 1]);
        unsigned M = ms & 0xFu;
        unsigned S = (ms >> 8) & 0xFu;
        if (n < N_H) {
            #pragma unroll
            for (int b = 0; b < 4; ++b) if ((M >> b) & 1u) {
                bool sp = (S >> b) & 1u;
                h2r[b]     += sp ? w[0] : -w[0];
                h2r[4 + b] += sp ? w[1] : -w[1];
            }
        } else {
            #pragma unroll
            for (int b = 0; b < 4; ++b) if ((M >> b) & 1u) {
                bool sp = (S >> b) & 1u;
                h1r[b]      += sp ? w[0] : -w[0];
                h1r[4 + b]  += sp ? w[1] : -w[1];
                h1r[8 + b]  += sp ? w[2] : -w[2];
                h1r[12 + b] += sp ? w[3] : -w[3];
            }
        }
        if ((t & 127) == 0 && t + 128 < T_TOT) refill(t + 128);
    };

    __syncthreads();   // ids_s visible
    int n0 = ids_s[0], n1 = ids_s[1];
    double wA[4], wB[4];
    loadrow(n0, wA);
    loadrow(n1, wB);
    refill(0);
    refill(128);
    __syncthreads();   // thr ring visible

    for (int t = 0; t < T_TOT; t += 2) {
        step(t, wA, n0);
        if (t + 2 < T_TOT) { n0 = ids_s[t + 2]; loadrow(n0, wA); }
        step(t + 1, wB, n1);
        if (t + 3 < T_TOT) { n1 = ids_s[t + 3]; loadrow(n1, wB); }
    }

    // epilogue: out = [x | s1 | s2], row stride 2560
    #pragma unroll
    for (int b = 0; b < 4; ++b) {
        size_t orow = (size_t)(b0 + b) * 2560;
        for (int c = tid; c < 1024; c += 256)
            out[orow + c] = x[(size_t)(b0 + b) * 1024 + c];
    }
    #pragma unroll
    for (int k = 0; k < 4; ++k)
        #pragma unroll
        for (int b = 0; b < 4; ++b)
            out[(size_t)(b0 + b) * 2560 + 1024 + k * 256 + tid] = (float)((s1m >> (k * 4 + b)) & 1u);
    #pragma unroll
    for (int k = 0; k < 2; ++k)
        #pragma unroll
        for (int b = 0; b < 4; ++b)
            out[(size_t)(b0 + b) * 2560 + 2048 + k * 256 + tid] = (float)((s2m >> (k * 4 + b)) & 1u);
}

// ---------------- launch ----------------
extern "C" void kernel_launch(void* const* d_in, const int* in_sizes, int n_in,
                              void* d_out, int out_size, void* d_ws, size_t ws_size,
                              hipStream_t stream) {
    const float* x   = (const float*)d_in[0];
    const float* s1i = (const float*)d_in[1];
    const float* s2i = (const float*)d_in[2];
    const float* W1  = (const float*)d_in[3];
    const float* b1  = (const float*)d_in[4];
    const float* W2  = (const float*)d_in[5];
    const float* b2  = (const float*)d_in[6];
    const float* u   = (const float*)d_in[7];
    const int*   ids = (const int*)d_in[8];
    float* out = (float*)d_out;

    char* ws = (char*)d_ws;
    double* W2Td = (double*)(ws);                       //  4 MB: [1024][512] f64 (W2 col-major)
    double* W2d  = (double*)(ws + ((size_t)4  << 20));  //  4 MB: [512][1024] f64
    float*  W1T  = (float*) (ws + ((size_t)8  << 20));  //  4 MB: [1024][1024] f32
    float*  W2Tf = (float*) (ws + ((size_t)12 << 20));  //  2 MB: [1024][512] f32
    double* h1g  = (double*)(ws + ((size_t)14 << 20));  // 16 MB: [2048][1024] f64
    double* h2g  = (double*)(ws + ((size_t)30 << 20));  //  8 MB: [2048][512] f64

    hipLaunchKernelGGL(prep_w1t, dim3(4096), dim3(256), 0, stream, W1, W1T);
    hipLaunchKernelGGL(prep_w2a, dim3(2048), dim3(256), 0, stream, W2, W2Td, W2Tf);
    hipLaunchKernelGGL(prep_w2b, dim3(2048), dim3(256), 0, stream, W2, W2d);
    hipLaunchKernelGGL(init_fields, dim3(256), dim3(256), 0, stream,
                       x, s1i, s2i, W1T, W2, W2Tf, b1, b2, h1g, h2g);
    hipLaunchKernelGGL(gibbs, dim3(512), dim3(256), 0, stream,
                       x, u, ids, W2Td, W2d, h1g, h2g, s1i, s2i, out);
}

// Round 2
// 3070.551 us; speedup vs baseline: 1.2809x; 1.2809x over previous
//
#include <hip/hip_runtime.h>
#include <math.h>

// Problem constants
#define B_TOT   2048
#define N_IN    1024
#define N_H     1024
#define N_OUT   512
#define N_UPD   1536
#define T_TOT   3072   // MAX_STEPS * N_UPD

// ---------------- prep kernels ----------------

// W1T[c*1024 + r] = W1[r*1024 + c]
__global__ void prep_w1t(const float* __restrict__ W1, float* __restrict__ W1T) {
    int idx = blockIdx.x * 256 + threadIdx.x;   // < 1024*1024
    int r = idx & 1023;
    int c = idx >> 10;
    W1T[(size_t)c * 1024 + r] = W1[(size_t)r * 1024 + c];
}

// W2Tf[c*512 + r] = W2[r*1024 + c]
__global__ void prep_w2tf(const float* __restrict__ W2, float* __restrict__ W2Tf) {
    int idx = blockIdx.x * 256 + threadIdx.x;   // < 512*1024
    int r = idx & 511;
    int c = idx >> 9;
    W2Tf[(size_t)c * 512 + r] = W2[(size_t)r * 1024 + c];
}

// WH[n][lane][j] = W2[(j*64+lane)][n]  -> hidden-flip row fragment, lane-contiguous
__global__ void prep_wh(const float* __restrict__ W2, float* __restrict__ WH) {
    int idx = blockIdx.x * 256 + threadIdx.x;   // < 1024*512
    int n = idx >> 9;
    int r = idx & 511;
    int l = r >> 3, j = r & 7;
    WH[idx] = W2[(size_t)(j * 64 + l) * 1024 + n];
}

// WO[nn][lane][j] = W2[nn][j*64+lane]  -> output-flip row fragment, lane-contiguous
__global__ void prep_wo(const float* __restrict__ W2, float* __restrict__ WO) {
    int idx = blockIdx.x * 256 + threadIdx.x;   // < 512*1024
    int nn = idx >> 10;
    int r = idx & 1023;
    int l = r >> 4, j = r & 15;
    WO[idx] = W2[(size_t)nn * 1024 + j * 64 + l];
}

// ---------------- init fields (fp64) ----------------
// Same math/order as round 1 (absmax 0.0), but mask reads prefetched as uint32
// groups of 4 and weight rows batch-loaded per group (hides the LDS latency
// that was serialized per-iteration before).
__global__ __launch_bounds__(256) void init_fields(
    const float* __restrict__ x, const float* __restrict__ s1i, const float* __restrict__ s2i,
    const float* __restrict__ W1T, const float* __restrict__ W2, const float* __restrict__ W2Tf,
    const float* __restrict__ b1, const float* __restrict__ b2,
    double* __restrict__ h1g, double* __restrict__ h2g)
{
    const int tid = threadIdx.x;
    const int b0 = blockIdx.x * 8;

    __shared__ unsigned char xm[1024];
    __shared__ unsigned char s2msk[512];
    __shared__ unsigned char s1msk[1024];

    for (int i = tid; i < 1024; i += 256) {
        unsigned m = 0;
        #pragma unroll
        for (int b = 0; b < 8; ++b) m |= (x[(size_t)(b0 + b) * 1024 + i] != 0.0f) << b;
        xm[i] = (unsigned char)m;
    }
    for (int j = tid; j < 512; j += 256) {
        unsigned m = 0;
        #pragma unroll
        for (int b = 0; b < 8; ++b) m |= (s2i[(size_t)(b0 + b) * 512 + j] != 0.0f) << b;
        s2msk[j] = (unsigned char)m;
    }
    for (int j = tid; j < 1024; j += 256) {
        unsigned m = 0;
        #pragma unroll
        for (int b = 0; b < 8; ++b) m |= (s1i[(size_t)(b0 + b) * 1024 + j] != 0.0f) << b;
        s1msk[j] = (unsigned char)m;
    }
    __syncthreads();

    double h1r[32];
    #pragma unroll
    for (int k = 0; k < 4; ++k) {
        double bv = (double)b1[k * 256 + tid];
        #pragma unroll
        for (int b = 0; b < 8; ++b) h1r[k * 8 + b] = bv;
    }
    double h2r[16];
    #pragma unroll
    for (int k = 0; k < 2; ++k) {
        double bv = (double)b2[k * 256 + tid];
        #pragma unroll
        for (int b = 0; b < 8; ++b) h2r[k * 8 + b] = bv;
    }

    // part 1: x @ W1^T  (1024 rows, 4 weights each, groups of 4 rows)
    {
        const unsigned* xmu = (const unsigned*)xm;
        unsigned mwn = xmu[0];
        for (int g = 0; g < 256; ++g) {
            unsigned mg = (unsigned)__builtin_amdgcn_readfirstlane((int)mwn);
            if (g + 1 < 256) mwn = xmu[g + 1];
            float wr[4][4];
            #pragma unroll
            for (int s = 0; s < 4; ++s) {
                const float* q = W1T + (size_t)(4 * g + s) * 1024 + tid;
                wr[s][0] = q[0]; wr[s][1] = q[256]; wr[s][2] = q[512]; wr[s][3] = q[768];
            }
            #pragma unroll
            for (int s = 0; s < 4; ++s) {
                unsigned m8 = (mg >> (8 * s)) & 0xFFu;
                if (m8) {
                    double d0 = (double)wr[s][0], d1 = (double)wr[s][1];
                    double d2 = (double)wr[s][2], d3 = (double)wr[s][3];
                    #pragma unroll
                    for (int b = 0; b < 8; ++b) if ((m8 >> b) & 1u) {
                        h1r[0 * 8 + b] += d0; h1r[1 * 8 + b] += d1;
                        h1r[2 * 8 + b] += d2; h1r[3 * 8 + b] += d3;
                    }
                }
            }
        }
    }
    // part 2: s2 @ W2  (512 rows, 4 weights each)
    {
        const unsigned* s2u = (const unsigned*)s2msk;
        unsigned mwn = s2u[0];
        for (int g = 0; g < 128; ++g) {
            unsigned mg = (unsigned)__builtin_amdgcn_readfirstlane((int)mwn);
            if (g + 1 < 128) mwn = s2u[g + 1];
            float wr[4][4];
            #pragma unroll
            for (int s = 0; s < 4; ++s) {
                const float* q = W2 + (size_t)(4 * g + s) * 1024 + tid;
                wr[s][0] = q[0]; wr[s][1] = q[256]; wr[s][2] = q[512]; wr[s][3] = q[768];
            }
            #pragma unroll
            for (int s = 0; s < 4; ++s) {
                unsigned m8 = (mg >> (8 * s)) & 0xFFu;
                if (m8) {
                    double d0 = (double)wr[s][0], d1 = (double)wr[s][1];
                    double d2 = (double)wr[s][2], d3 = (double)wr[s][3];
                    #pragma unroll
                    for (int b = 0; b < 8; ++b) if ((m8 >> b) & 1u) {
                        h1r[0 * 8 + b] += d0; h1r[1 * 8 + b] += d1;
                        h1r[2 * 8 + b] += d2; h1r[3 * 8 + b] += d3;
                    }
                }
            }
        }
    }
    // part 3: s1 @ W2^T  (1024 rows, 2 weights each)
    {
        const unsigned* s1u = (const unsigned*)s1msk;
        unsigned mwn = s1u[0];
        for (int g = 0; g < 256; ++g) {
            unsigned mg = (unsigned)__builtin_amdgcn_readfirstlane((int)mwn);
            if (g + 1 < 256) mwn = s1u[g + 1];
            float wr[4][2];
            #pragma unroll
            for (int s = 0; s < 4; ++s) {
                const float* q = W2Tf + (size_t)(4 * g + s) * 512 + tid;
                wr[s][0] = q[0]; wr[s][1] = q[256];
            }
            #pragma unroll
            for (int s = 0; s < 4; ++s) {
                unsigned m8 = (mg >> (8 * s)) & 0xFFu;
                if (m8) {
                    double d0 = (double)wr[s][0], d1 = (double)wr[s][1];
                    #pragma unroll
                    for (int b = 0; b < 8; ++b) if ((m8 >> b) & 1u) {
                        h2r[0 * 8 + b] += d0; h2r[1 * 8 + b] += d1;
                    }
                }
            }
        }
    }

    #pragma unroll
    for (int k = 0; k < 4; ++k)
        #pragma unroll
        for (int b = 0; b < 8; ++b)
            h1g[(size_t)(b0 + b) * 1024 + k * 256 + tid] = h1r[k * 8 + b];
    #pragma unroll
    for (int k = 0; k < 2; ++k)
        #pragma unroll
        for (int b = 0; b < 8; ++b)
            h2g[(size_t)(b0 + b) * 512 + k * 256 + tid] = h2r[k * 8 + b];
}

// ---------------- Gibbs chain: one wave per 2 batch rows, NO barriers ----------------

__device__ __forceinline__ double rdl_f64(double v, int sl) {
    union { double d; int i[2]; } a, b;
    a.d = v;
    b.i[0] = __builtin_amdgcn_readlane(a.i[0], sl);
    b.i[1] = __builtin_amdgcn_readlane(a.i[1], sl);
    return b.d;
}

__global__ __launch_bounds__(64, 1) void gibbs(
    const float* __restrict__ x, const float* __restrict__ u, const int* __restrict__ ids,
    const float* __restrict__ WH, const float* __restrict__ WO,
    const double* __restrict__ h1g, const double* __restrict__ h2g,
    const float* __restrict__ s1i, const float* __restrict__ s2i,
    float* __restrict__ out)
{
    const int lane = threadIdx.x;          // 0..63
    const int b0 = blockIdx.x * 2;         // batch pair

    // fields in registers: unit m = k*64 + lane
    double h1r[32], h2r[16];
    #pragma unroll
    for (int k = 0; k < 16; ++k) h1r[k]      = h1g[(size_t)b0 * 1024 + k * 64 + lane];
    #pragma unroll
    for (int k = 0; k < 16; ++k) h1r[16 + k] = h1g[(size_t)(b0 + 1) * 1024 + k * 64 + lane];
    #pragma unroll
    for (int k = 0; k < 8; ++k) h2r[k]     = h2g[(size_t)b0 * 512 + k * 64 + lane];
    #pragma unroll
    for (int k = 0; k < 8; ++k) h2r[8 + k] = h2g[(size_t)(b0 + 1) * 512 + k * 64 + lane];

    // state bitmasks: s1b bits 0..15 batch0, 16..31 batch1; s2b bits 0..7 / 8..15
    unsigned s1b = 0, s2b = 0;
    #pragma unroll
    for (int k = 0; k < 16; ++k) {
        s1b |= (s1i[(size_t)b0 * 1024 + k * 64 + lane] != 0.0f ? 1u : 0u) << k;
        s1b |= (s1i[(size_t)(b0 + 1) * 1024 + k * 64 + lane] != 0.0f ? 1u : 0u) << (16 + k);
    }
    #pragma unroll
    for (int k = 0; k < 8; ++k) {
        s2b |= (s2i[(size_t)b0 * 512 + k * 64 + lane] != 0.0f ? 1u : 0u) << k;
        s2b |= (s2i[(size_t)(b0 + 1) * 512 + k * 64 + lane] != 0.0f ? 1u : 0u) << (8 + k);
    }

    // temperature constants (bit-identical to round-1 formula)
    const double T1 = (double)(float)(2.0 / exp((double)1 / 5.0));

    // threshold pipeline: lane l of window W holds thr for step W*64+l (batch0/1)
    auto thrcalc = [&](float2 uv, int tp, double& o0, double& o1) {
        double T = (tp >= N_UPD) ? T1 : 2.0;
        double u0 = (double)uv.x, u1 = (double)uv.y;
        o0 = T * (log(u0) - log1p(-u0));
        o1 = T * (log(u1) - log1p(-u1));
    };
    double tc0, tc1, tn0, tn1;
    float2 uP;
    {
        float2 uA = *(const float2*)(u + (size_t)(0 + lane) * 2048 + b0);
        float2 uB = *(const float2*)(u + (size_t)(64 + lane) * 2048 + b0);
        uP        = *(const float2*)(u + (size_t)(128 + lane) * 2048 + b0);
        thrcalc(uA, 0 + lane, tc0, tc1);
        thrcalc(uB, 64 + lane, tn0, tn1);
    }

    float w0[16], w1[16], w2[16], w3[16];
    auto loadw = [&](int n, float (&w)[16]) {
        if (n < N_H) {
            const float4* p = (const float4*)(WH + ((size_t)n << 9) + (lane << 3));
            float4 a = p[0], b = p[1];
            w[0] = a.x; w[1] = a.y; w[2] = a.z; w[3] = a.w;
            w[4] = b.x; w[5] = b.y; w[6] = b.z; w[7] = b.w;
        } else {
            const float4* p = (const float4*)(WO + ((size_t)(n - N_H) << 10) + (lane << 4));
            float4 a = p[0], b = p[1], c = p[2], d = p[3];
            w[0]  = a.x; w[1]  = a.y; w[2]  = a.z; w[3]  = a.w;
            w[4]  = b.x; w[5]  = b.y; w[6]  = b.z; w[7]  = b.w;
            w[8]  = c.x; w[9]  = c.y; w[10] = c.z; w[11] = c.w;
            w[12] = d.x; w[13] = d.y; w[14] = d.z; w[15] = d.w;
        }
    };

    auto step = [&](int t, const float (&w)[16], int n) {
        int sl = t & 63;
        double th0 = rdl_f64(tc0, sl), th1 = rdl_f64(tc1, sl);
        if (n < N_H) {
            int k = n >> 6, ow = n & 63;
            unsigned long long m0 = 0, m1 = 0;
            #pragma unroll
            for (int kk = 0; kk < 16; ++kk) if (kk == k) {
                m0 = __ballot(h1r[kk] > th0);
                m1 = __ballot(h1r[16 + kk] > th1);
            }
            int a0 = (int)((m0 >> ow) & 1), a1 = (int)((m1 >> ow) & 1);
            unsigned op = (unsigned)__builtin_amdgcn_readlane((int)s1b, ow);
            int o0 = (int)((op >> k) & 1u), o1 = (int)((op >> (16 + k)) & 1u);
            int c0 = a0 ^ o0, c1 = a1 ^ o1;
            if (c0 | c1) {
                unsigned xm = (c0 ? (1u << k) : 0u) | (c1 ? (1u << (16 + k)) : 0u);
                s1b ^= (lane == ow) ? xm : 0u;
                double d0 = (double)(a0 - o0), d1 = (double)(a1 - o1);
                #pragma unroll
                for (int j = 0; j < 8; ++j) {
                    double wd = (double)w[j];
                    h2r[j]     = fma(d0, wd, h2r[j]);
                    h2r[8 + j] = fma(d1, wd, h2r[8 + j]);
                }
            }
        } else {
            int nn = n - N_H;
            int k = nn >> 6, ow = nn & 63;
            unsigned long long m0 = 0, m1 = 0;
            #pragma unroll
            for (int kk = 0; kk < 8; ++kk) if (kk == k) {
                m0 = __ballot(h2r[kk] > th0);
                m1 = __ballot(h2r[8 + kk] > th1);
            }
            int a0 = (int)((m0 >> ow) & 1), a1 = (int)((m1 >> ow) & 1);
            unsigned op = (unsigned)__builtin_amdgcn_readlane((int)s2b, ow);
            int o0 = (int)((op >> k) & 1u), o1 = (int)((op >> (8 + k)) & 1u);
            int c0 = a0 ^ o0, c1 = a1 ^ o1;
            if (c0 | c1) {
                unsigned xm = (c0 ? (1u << k) : 0u) | (c1 ? (1u << (8 + k)) : 0u);
                s2b ^= (lane == ow) ? xm : 0u;
                double d0 = (double)(a0 - o0), d1 = (double)(a1 - o1);
                #pragma unroll
                for (int j = 0; j < 16; ++j) {
                    double wd = (double)w[j];
                    h1r[j]      = fma(d0, wd, h1r[j]);
                    h1r[16 + j] = fma(d1, wd, h1r[16 + j]);
                }
            }
        }
    };

    // depth-4 row prefetch, ids prefetched ~8 steps ahead (uniform s_loads)
    int n0 = ids[0], n1 = ids[1], n2 = ids[2], n3 = ids[3];
    int n4 = ids[4], n5 = ids[5], n6 = ids[6], n7 = ids[7];
    loadw(n0, w0); loadw(n1, w1); loadw(n2, w2); loadw(n3, w3);

    for (int t = 0; t < T_TOT; t += 4) {
        step(t,     w0, n0); loadw(n4, w0);
        step(t + 1, w1, n1); loadw(n5, w1);
        step(t + 2, w2, n2); loadw(n6, w2);
        step(t + 3, w3, n3); loadw(n7, w3);
        n0 = n4; n1 = n5; n2 = n6; n3 = n7;
        int tb = t + 8;
        n4 = ids[tb     < T_TOT ? tb     : T_TOT - 1];
        n5 = ids[tb + 1 < T_TOT ? tb + 1 : T_TOT - 1];
        n6 = ids[tb + 2 < T_TOT ? tb + 2 : T_TOT - 1];
        n7 = ids[tb + 3 < T_TOT ? tb + 3 : T_TOT - 1];
        if (((t + 4) & 63) == 0 && (t + 4) < T_TOT) {
            tc0 = tn0; tc1 = tn1;
            thrcalc(uP, t + 68 + lane, tn0, tn1);
            int tp = t + 132 + lane; if (tp > T_TOT - 1) tp = T_TOT - 1;
            uP = *(const float2*)(u + (size_t)tp * 2048 + b0);
        }
    }

    // epilogue: out rows = [x | s1 | s2], stride 2560
    {
        const float4* xr0 = (const float4*)(x + (size_t)b0 * 1024);
        const float4* xr1 = (const float4*)(x + (size_t)(b0 + 1) * 1024);
        float4* or0 = (float4*)(out + (size_t)b0 * 2560);
        float4* or1 = (float4*)(out + (size_t)(b0 + 1) * 2560);
        #pragma unroll
        for (int i = 0; i < 4; ++i) {
            or0[i * 64 + lane] = xr0[i * 64 + lane];
            or1[i * 64 + lane] = xr1[i * 64 + lane];
        }
    }
    #pragma unroll
    for (int k = 0; k < 16; ++k) {
        out[(size_t)b0 * 2560 + 1024 + k * 64 + lane]       = (float)((s1b >> k) & 1u);
        out[(size_t)(b0 + 1) * 2560 + 1024 + k * 64 + lane] = (float)((s1b >> (16 + k)) & 1u);
    }
    #pragma unroll
    for (int k = 0; k < 8; ++k) {
        out[(size_t)b0 * 2560 + 2048 + k * 64 + lane]       = (float)((s2b >> k) & 1u);
        out[(size_t)(b0 + 1) * 2560 + 2048 + k * 64 + lane] = (float)((s2b >> (8 + k)) & 1u);
    }
}

// ---------------- launch ----------------
extern "C" void kernel_launch(void* const* d_in, const int* in_sizes, int n_in,
                              void* d_out, int out_size, void* d_ws, size_t ws_size,
                              hipStream_t stream) {
    const float* x   = (const float*)d_in[0];
    const float* s1i = (const float*)d_in[1];
    const float* s2i = (const float*)d_in[2];
    const float* W1  = (const float*)d_in[3];
    const float* b1  = (const float*)d_in[4];
    const float* W2  = (const float*)d_in[5];
    const float* b2  = (const float*)d_in[6];
    const float* u   = (const float*)d_in[7];
    const int*   ids = (const int*)d_in[8];
    float* out = (float*)d_out;

    char* ws = (char*)d_ws;
    float*  W1T  = (float*) (ws);                       //  4 MB
    float*  W2Tf = (float*) (ws + ((size_t)4  << 20));  //  2 MB
    float*  WH   = (float*) (ws + ((size_t)6  << 20));  //  2 MB
    float*  WO   = (float*) (ws + ((size_t)8  << 20));  //  2 MB
    double* h1g  = (double*)(ws + ((size_t)10 << 20));  // 16 MB
    double* h2g  = (double*)(ws + ((size_t)26 << 20));  //  8 MB

    hipLaunchKernelGGL(prep_w1t,  dim3(4096), dim3(256), 0, stream, W1, W1T);
    hipLaunchKernelGGL(prep_w2tf, dim3(2048), dim3(256), 0, stream, W2, W2Tf);
    hipLaunchKernelGGL(prep_wh,   dim3(2048), dim3(256), 0, stream, W2, WH);
    hipLaunchKernelGGL(prep_wo,   dim3(2048), dim3(256), 0, stream, W2, WO);
    hipLaunchKernelGGL(init_fields, dim3(256), dim3(256), 0, stream,
                       x, s1i, s2i, W1T, W2, W2Tf, b1, b2, h1g, h2g);
    hipLaunchKernelGGL(gibbs, dim3(1024), dim3(64), 0, stream,
                       x, u, ids, WH, WO, h1g, h2g, s1i, s2i, out);
}